// Round 11
// baseline (2978.841 us; speedup 1.0000x reference)
//
#include <hip/hip_runtime.h>
#include <math.h>

// Problem constants
#define B_   64
#define P_   196      // 14*14 pixels
#define E_   2048
#define L_   30
#define T_   29       // L-1 decode steps
#define V_   10000
#define EMB_ 512
#define AML_ 768
#define ADL_ 500
#define D_   1012     // 512+ADL
#define A_   1012
#define G4_  4048     // 4*D
#define XK_  2560     // EMB+E

typedef unsigned short u16;
typedef __attribute__((ext_vector_type(8))) short bf16x8;
typedef __attribute__((ext_vector_type(4))) float f32x4;

__device__ __forceinline__ float sigf(float x) { return 1.f / (1.f + __expf(-x)); }
__device__ __forceinline__ float tanhf_fast(float x) { return 1.f - 2.f / (__expf(2.f * x) + 1.f); }
__device__ __forceinline__ u16 f2bf(float f) {
    unsigned u = __float_as_uint(f);
    return (u16)((u + 0x7FFFu + ((u >> 16) & 1u)) >> 16);
}
__device__ __forceinline__ float bf2f(u16 v) { return __uint_as_float(((unsigned)v) << 16); }

// ---------------- setup ----------------
__global__ void k_setup(const int* __restrict__ clen, const int* __restrict__ caps,
                        float* __restrict__ out_caps, float* __restrict__ out_dlens,
                        float* __restrict__ out_sind,
                        int* __restrict__ sort_ind, int* __restrict__ dlens_i,
                        int* __restrict__ nact, int* __restrict__ caps_s,
                        int* __restrict__ gcnt)
{
    __shared__ int lens[B_];
    int t = threadIdx.x;
    if (t < B_) lens[t] = clen[t];
    if (t < 64) gcnt[t] = 0;
    __syncthreads();
    if (t < B_) {
        int my = lens[t];
        int rank = 0;
        for (int j = 0; j < B_; ++j) {
            int lj = lens[j];
            if (lj > my || (lj == my && j < t)) rank++;  // stable descending
        }
        sort_ind[rank] = t;
    }
    __syncthreads();
    if (t < B_) {
        int orig = sort_ind[t];
        int dl = lens[orig] - 1;
        dlens_i[t] = dl;
        out_dlens[t] = (float)dl;
        out_sind[t] = (float)orig;
        for (int j = 0; j < L_; ++j) {
            int cv = caps[orig * L_ + j];
            caps_s[t * L_ + j] = cv;
            out_caps[t * L_ + j] = (float)cv;
        }
    }
    __syncthreads();
    if (t < T_) {
        int cnt = 0;
        for (int j = 0; j < B_; ++j) cnt += (dlens_i[j] > t) ? 1 : 0;
        nact[t] = cnt;
    }
}

// ---------------- zero entire output buffer ----------------
__global__ void k_zero(float4* __restrict__ p, long n4)
{
    long i = (long)blockIdx.x * 256 + threadIdx.x;
    if (i < n4) p[i] = make_float4(0.f, 0.f, 0.f, 0.f);
}

// ---------------- gather + fp32->bf16 convert enc rows into sorted order ----------------
__global__ void k_cvt_enc(const float* __restrict__ enc, const int* __restrict__ sort_ind,
                          u16* __restrict__ A_bf)
{
    int row = blockIdx.y;                 // 0..12543  (b*196+p sorted)
    int b = row / 196, p = row - b * 196;
    int e4 = (blockIdx.x * 256 + threadIdx.x) * 4;   // 0..2044
    const float* src = enc + ((long)sort_ind[b] * 196 + p) * E_ + e4;
    float4 v = *(const float4*)src;
    unsigned lo = (unsigned)f2bf(v.x) | ((unsigned)f2bf(v.y) << 16);
    unsigned hi = (unsigned)f2bf(v.z) | ((unsigned)f2bf(v.w) << 16);
    uint2 pk; pk.x = lo; pk.y = hi;
    *(uint2*)(A_bf + (long)row * E_ + e4) = pk;
}

// ---------------- tiled transpose + convert: fp32 [K][N] -> bf16 [Np][Kp] (pads=0) ----
__global__ void k_transpose(const float* __restrict__ src, u16* __restrict__ dst,
                            int K, int N, int Kp, int Np)
{
    __shared__ float tile[32][33];
    int n0 = blockIdx.x * 32, k0 = blockIdx.y * 32;
    int tx = threadIdx.x, ty = threadIdx.y;   // (32,8)
    for (int r = ty; r < 32; r += 8) {
        int k = k0 + r, n = n0 + tx;
        tile[r][tx] = (k < K && n < N) ? src[(long)k * N + n] : 0.f;
    }
    __syncthreads();
    for (int r = ty; r < 32; r += 8) {
        int n = n0 + r, k = k0 + tx;
        if (n < Np && k < Kp) dst[(long)n * Kp + k] = f2bf(tile[tx][r]);
    }
}

// ---------------- enc mean -> dec_in_bf cols [0,2048) ----------------
__global__ void k_encmean(const float* __restrict__ enc, const int* __restrict__ sort_ind,
                          u16* __restrict__ dec_in)
{
    int b = blockIdx.y;
    int e = blockIdx.x * 256 + threadIdx.x;   // < 2048
    int orig = sort_ind[b];
    const float* src = enc + (long)orig * P_ * E_ + e;
    float s = 0.f;
    for (int p = 0; p < P_; ++p) s += src[(long)p * E_];
    dec_in[(long)b * XK_ + e] = f2bf(s * (1.f / 196.f));
}

// ---------------- context -> dec_in_bf cols [2048,2560), pad 0 ----------------
__global__ void k_ctx(const float* __restrict__ arts, const float* __restrict__ W_par,
                      const float* __restrict__ b_par, const int* __restrict__ sort_ind,
                      u16* __restrict__ dec_in)
{
    int b = blockIdx.y;
    int k = blockIdx.x * 256 + threadIdx.x;   // < 512
    if (k >= 512) return;
    float s = 0.f;
    if (k < ADL_) {
        int orig = sort_ind[b];
        const float* ar = arts + (long)orig * AML_;
        s = b_par[k];
        for (int m = 0; m < AML_; ++m) s = fmaf(ar[m], W_par[m * ADL_ + k], s);
    }
    dec_in[(long)b * XK_ + E_ + k] = f2bf(s);
}

// ---------------- emb gather for ALL timesteps (loop-invariant) ----------------
__global__ void k_emb_all(const float* __restrict__ E_emb, const int* __restrict__ caps_s,
                          u16* __restrict__ emb_all)
{
    int t = blockIdx.x;   // 0..28
    int b = blockIdx.y;
    int tok = caps_s[b * L_ + t];
    for (int k = threadIdx.x; k < EMB_; k += 256)
        emb_all[((long)t * B_ + b) * EMB_ + k] = f2bf(E_emb[(long)tok * EMB_ + k]);
}

// ---------------- att1 MFMA with cooperative LDS A-staging + double buffer ----------------
// block = 256 thr, tile M=64 N=256. A-tile [64][32] staged once/block (uint4 = full row).
__global__ void __launch_bounds__(256) k_att1_mfma(
    const u16* __restrict__ A, const u16* __restrict__ W,
    const float* __restrict__ bias, u16* __restrict__ Yb)
{
    __shared__ u16 As[2][64][40];   // 80B row stride: reads & 16B writes bank-even
    int w = threadIdx.x >> 6, lane = threadIdx.x & 63;
    int lr = lane & 15, lk = (lane >> 4) * 8;
    int n0 = blockIdx.x * 256 + w * 64;
    int r0 = blockIdx.y * 64;
    int arow = threadIdx.x >> 2;            // 0..63
    int akseg = (threadIdx.x & 3) * 8;      // 0,8,16,24 (u16 units; 16B each)
    const u16* ag = A + (long)(r0 + arow) * E_ + akseg;

    f32x4 acc[4][4];
#pragma unroll
    for (int i = 0; i < 4; ++i)
#pragma unroll
        for (int j = 0; j < 4; ++j) acc[i][j] = (f32x4){0.f, 0.f, 0.f, 0.f};
    const u16* wp = W + (long)(n0 + lr) * E_ + lk;

    // preload k=0 A-tile (16B per thread -> full 64x32 tile)
    *(uint4*)&As[0][arow][akseg] = *(const uint4*)(ag);
    __syncthreads();

    for (int k = 0; k < E_; k += 32) {
        int buf = (k >> 5) & 1;
        bool more = (k + 32) < E_;
        uint4 pre;
        if (more) pre = *(const uint4*)(ag + k + 32);   // prefetch next A-tile
        bf16x8 bf[4], af[4];
#pragma unroll
        for (int nt = 0; nt < 4; ++nt) bf[nt] = *(const bf16x8*)(wp + (long)nt * 16 * E_ + k);
#pragma unroll
        for (int mt = 0; mt < 4; ++mt) af[mt] = *(const bf16x8*)&As[buf][mt * 16 + lr][lk];
#pragma unroll
        for (int mt = 0; mt < 4; ++mt)
#pragma unroll
            for (int nt = 0; nt < 4; ++nt)
                acc[mt][nt] = __builtin_amdgcn_mfma_f32_16x16x32_bf16(af[mt], bf[nt], acc[mt][nt], 0, 0, 0);
        if (more) *(uint4*)&As[buf ^ 1][arow][akseg] = pre;
        __syncthreads();
    }
#pragma unroll
    for (int mt = 0; mt < 4; ++mt) {
#pragma unroll
        for (int nt = 0; nt < 4; ++nt) {
            int n = n0 + nt * 16 + lr;
            float bv = (n < A_) ? bias[n] : 0.f;
#pragma unroll
            for (int j = 0; j < 4; ++j) {
                int row = r0 + mt * 16 + (lane >> 4) * 4 + j;
                u16 outv = (n < A_) ? f2bf(acc[mt][nt][j] + bv) : (u16)0;
                Yb[(long)row * 1024 + n] = outv;
            }
        }
    }
}

// ---------------- skinny MFMA (h0/c0) ----------------
template <int ACT, int OUT, int PADZ>
__global__ void __launch_bounds__(256) k_skinny(
    const u16* __restrict__ A1, const u16* __restrict__ W1, int K1,
    const float* __restrict__ bias1, void* __restrict__ Yv,
    long ldY, long offY, int Nmax,
    const int* __restrict__ nact, int t)
{
    int Bact = (t >= 0) ? nact[t] : B_;
    if (Bact <= 0) return;
    int mmax = (Bact + 15) >> 4;
    int w = threadIdx.x >> 6, lane = threadIdx.x & 63;
    int lr = lane & 15, lk = (lane >> 4) * 8;
    int n0 = blockIdx.x * 64 + w * 16;
    f32x4 acc[4];
#pragma unroll
    for (int m = 0; m < 4; ++m) acc[m] = (f32x4){0.f, 0.f, 0.f, 0.f};

    int n = n0 + lr;
    int nc = n < Nmax ? n : Nmax - 1;
    const u16* a1p = A1 + (long)lr * K1 + lk;
    const u16* w1p = W1 + (long)nc * K1 + lk;
    for (int k = 0; k < K1; k += 32) {
        bf16x8 bw = *(const bf16x8*)(w1p + k);
#pragma unroll
        for (int m = 0; m < 4; ++m)
            if (m < mmax) {
                bf16x8 aw = *(const bf16x8*)(a1p + (long)m * 16 * K1 + k);
                acc[m] = __builtin_amdgcn_mfma_f32_16x16x32_bf16(aw, bw, acc[m], 0, 0, 0);
            }
    }
    float bv = (n < Nmax) ? bias1[n] : 0.f;
#pragma unroll
    for (int m = 0; m < 4; ++m) {
        if (m < mmax) {
#pragma unroll
            for (int j = 0; j < 4; ++j) {
                int b = m * 16 + (lane >> 4) * 4 + j;
                if (b < Bact) {
                    float v = acc[m][j] + bv;
                    if (ACT == 1) v = sigf(v);
                    if (n < Nmax) {
                        if (OUT == 1) ((u16*)Yv)[(long)b * ldY + offY + n] = f2bf(v);
                        else          ((float*)Yv)[(long)b * ldY + offY + n] = v;
                    } else if (PADZ) {
                        if (OUT == 1) ((u16*)Yv)[(long)b * ldY + offY + n] = 0;
                        else          ((float*)Yv)[(long)b * ldY + offY + n] = 0.f;
                    }
                }
            }
        }
    }
}

// ---------------- batched emb @ W_ih (loop-invariant): gemb_all[t][b][q*1024+n] ----------------
// grid (16, 29)
__global__ void __launch_bounds__(256) k_gemb(
    const u16* __restrict__ emb_all, const u16* __restrict__ WT_ih,
    float* __restrict__ gemb_all)
{
    int t = blockIdx.y;
    int w = threadIdx.x >> 6, lane = threadIdx.x & 63;
    int lr = lane & 15, lk = (lane >> 4) * 8;
    int n0 = blockIdx.x * 256 + w * 64;
    f32x4 acc[4][4];
#pragma unroll
    for (int i = 0; i < 4; ++i)
#pragma unroll
        for (int j = 0; j < 4; ++j) acc[i][j] = (f32x4){0.f, 0.f, 0.f, 0.f};
    const u16* ap = emb_all + ((long)t * B_ + lr) * EMB_ + lk;
    long wrow[4];
#pragma unroll
    for (int nt = 0; nt < 4; ++nt) {
        int j = n0 + nt * 16 + lr;
        int q = j >> 10, d = j & 1023;
        wrow[nt] = (long)q * D_ + (d < D_ ? d : D_ - 1);
    }
    for (int k = 0; k < EMB_; k += 32) {
        bf16x8 af[4], bf[4];
#pragma unroll
        for (int mt = 0; mt < 4; ++mt) af[mt] = *(const bf16x8*)(ap + (long)mt * 16 * EMB_ + k);
#pragma unroll
        for (int nt = 0; nt < 4; ++nt) bf[nt] = *(const bf16x8*)(WT_ih + wrow[nt] * XK_ + lk + k);
#pragma unroll
        for (int mt = 0; mt < 4; ++mt)
#pragma unroll
            for (int nt = 0; nt < 4; ++nt)
                acc[mt][nt] = __builtin_amdgcn_mfma_f32_16x16x32_bf16(af[mt], bf[nt], acc[mt][nt], 0, 0, 0);
    }
#pragma unroll
    for (int nt = 0; nt < 4; ++nt) {
        int j = n0 + nt * 16 + lr;
#pragma unroll
        for (int mt = 0; mt < 4; ++mt) {
#pragma unroll
            for (int jj = 0; jj < 4; ++jj) {
                int b = mt * 16 + (lane >> 4) * 4 + jj;
                gemb_all[((long)t * B_ + b) * 4096 + j] = acc[mt][nt][jj];
            }
        }
    }
}

// ---------------- stage 1: att2(Kx2) + fb(Kx2) + h@W_hh partials (Kx2) ----------------
// grid 224: blocks 0-95 = att2fb (round-5 verified); blocks 96-223 = gh partials.
__global__ void __launch_bounds__(256) k_hg(
    const u16* __restrict__ h_bf, const u16* __restrict__ WT_dec,
    const u16* __restrict__ WT_fb, const u16* __restrict__ WT_hh,
    const float* __restrict__ b_dec, const float* __restrict__ b_fb,
    float* __restrict__ att2p, float* __restrict__ fbp, float* __restrict__ ghp,
    const int* __restrict__ nact, int t)
{
    int Bact = nact[t];
    if (Bact <= 0) return;
    int mmax = (Bact + 15) >> 4;
    int w = threadIdx.x >> 6, lane = threadIdx.x & 63;
    int lr = lane & 15, lk = (lane >> 4) * 8;

    if (blockIdx.x < 96) {
        int kh = blockIdx.x >= 48;
        int nb = blockIdx.x - (kh ? 48 : 0);
        int isfb = nb >= 16;
        const u16* W = isfb ? WT_fb : WT_dec;
        const float* bias = isfb ? b_fb : b_dec;
        int Nmax = isfb ? E_ : A_;
        int nb2 = isfb ? nb - 16 : nb;
        long ldY = isfb ? (long)E_ : 1024L;
        float* Y = (isfb ? fbp : att2p) + (long)kh * B_ * ldY;

        int n = nb2 * 64 + w * 16 + lr;
        int nc = n < Nmax ? n : Nmax - 1;
        int k0 = kh * 512;
        f32x4 acc[4];
#pragma unroll
        for (int m = 0; m < 4; ++m) acc[m] = (f32x4){0.f, 0.f, 0.f, 0.f};
        const u16* ap = h_bf + (long)lr * 1024 + k0 + lk;
        const u16* wp = W + (long)nc * 1024 + k0 + lk;
        for (int k = 0; k < 512; k += 32) {
            bf16x8 bw = *(const bf16x8*)(wp + k);
#pragma unroll
            for (int m = 0; m < 4; ++m)
                if (m < mmax) {
                    bf16x8 aw = *(const bf16x8*)(ap + (long)m * 16 * 1024 + k);
                    acc[m] = __builtin_amdgcn_mfma_f32_16x16x32_bf16(aw, bw, acc[m], 0, 0, 0);
                }
        }
        if (n >= Nmax) return;
        float bv = (kh == 0) ? bias[n] : 0.f;
#pragma unroll
        for (int m = 0; m < 4; ++m) {
            if (m < mmax) {
#pragma unroll
                for (int j = 0; j < 4; ++j) {
                    int b = m * 16 + (lane >> 4) * 4 + j;
                    if (b < Bact) Y[(long)b * ldY + n] = acc[m][j] + bv;
                }
            }
        }
    } else {
        int u = blockIdx.x - 96;           // 0..127
        int kh2 = u >> 6, nb = u & 63;
        int q = w;                          // wave = gate quadrant
        int n = nb * 16 + lr;
        int nc = n < D_ ? n : D_ - 1;
        int k0 = kh2 * 512;
        f32x4 acc[4];
#pragma unroll
        for (int m = 0; m < 4; ++m) acc[m] = (f32x4){0.f, 0.f, 0.f, 0.f};
        const u16* ap = h_bf + (long)lr * 1024 + k0 + lk;
        const u16* wp = WT_hh + ((long)q * D_ + nc) * 1024 + k0 + lk;
        for (int k = 0; k < 512; k += 32) {
            bf16x8 bw = *(const bf16x8*)(wp + k);
#pragma unroll
            for (int m = 0; m < 4; ++m)
                if (m < mmax) {
                    bf16x8 aw = *(const bf16x8*)(ap + (long)m * 16 * 1024 + k);
                    acc[m] = __builtin_amdgcn_mfma_f32_16x16x32_bf16(aw, bw, acc[m], 0, 0, 0);
                }
        }
#pragma unroll
        for (int m = 0; m < 4; ++m) {
            if (m < mmax) {
#pragma unroll
                for (int j = 0; j < 4; ++j) {
                    int bb = m * 16 + (lane >> 4) * 4 + j;
                    if (bb < Bact)
                        ghp[((long)kh2 * B_ + bb) * 4096 + q * 1024 + n] = acc[m][j];
                }
            }
        }
    }
}

// ---------------- scores: relu(att1_bf + att2p0 + att2p1) @ W_full + b_full ----------------
__global__ void k_scores(const u16* __restrict__ att1, const float* __restrict__ att2p,
                         const float* __restrict__ W_full, const float* __restrict__ b_full,
                         float* __restrict__ scores, const int* __restrict__ nact, int t)
{
    int b = blockIdx.y;
    if (b >= nact[t]) return;
    int wv = threadIdx.x >> 6;
    int lane = threadIdx.x & 63;
    int p = blockIdx.x * 4 + wv;   // 49*4 = 196
    const u16* a1 = att1 + ((long)b * P_ + p) * 1024;
    const float* a20 = att2p + (long)b * 1024;
    const float* a21 = att2p + (long)B_ * 1024 + (long)b * 1024;
    float acc = 0.f;
    for (int j2 = lane; j2 < 506; j2 += 64) {
        unsigned pk = *(const unsigned*)(a1 + 2 * j2);
        float2 p0 = *(const float2*)(a20 + 2 * j2);
        float2 p1 = *(const float2*)(a21 + 2 * j2);
        float2 wv2 = *(const float2*)(W_full + 2 * j2);
        float v0 = bf2f((u16)(pk & 0xFFFF)) + p0.x + p1.x;
        float v1 = bf2f((u16)(pk >> 16)) + p0.y + p1.y;
        v0 = v0 > 0.f ? v0 : 0.f;
        v1 = v1 > 0.f ? v1 : 0.f;
        acc = fmaf(v0, wv2.x, acc);
        acc = fmaf(v1, wv2.y, acc);
    }
    for (int m = 32; m >= 1; m >>= 1) acc += __shfl_xor(acc, m);
    if (lane == 0) scores[b * P_ + p] = acc + b_full[0];
}

// ---------------- awe + local softmax (+alphas) ----------------
// grid (9, 64): blocks 0-7 -> awe_buf cols; block 8 -> alphas_out
__global__ void __launch_bounds__(256) k_awe_x(
    const u16* __restrict__ A_bf, const float* __restrict__ scores,
    const float* __restrict__ fbp, u16* __restrict__ awe_buf,
    float* __restrict__ alphas_out, const int* __restrict__ nact, int t)
{
    int b = blockIdx.y;
    if (b >= nact[t]) return;
    int tid = threadIdx.x;
    int w = tid >> 6, lane = tid & 63;
    __shared__ float al[P_];
    __shared__ float red[4];
    float v = (tid < P_) ? scores[b * P_ + tid] : -1e30f;
    float m = v;
    for (int s = 32; s >= 1; s >>= 1) m = fmaxf(m, __shfl_xor(m, s));
    if (lane == 0) red[w] = m;
    __syncthreads();
    m = fmaxf(fmaxf(red[0], red[1]), fmaxf(red[2], red[3]));
    float e = (tid < P_) ? __expf(v - m) : 0.f;
    float s_ = e;
    for (int s = 32; s >= 1; s >>= 1) s_ += __shfl_xor(s_, s);
    __syncthreads();
    if (lane == 0) red[w] = s_;
    __syncthreads();
    s_ = red[0] + red[1] + red[2] + red[3];
    if (tid < P_) al[tid] = e / s_;
    __syncthreads();

    if (blockIdx.x < 8) {
        int e0 = blockIdx.x * 256 + tid;
        const u16* src = A_bf + (long)b * P_ * E_ + e0;
        float s0 = 0.f, s1 = 0.f, s2 = 0.f, s3 = 0.f;
        for (int p = 0; p < P_; p += 4) {
            s0 = fmaf(al[p],     bf2f(src[(long)p * E_]), s0);
            s1 = fmaf(al[p + 1], bf2f(src[(long)(p + 1) * E_]), s1);
            s2 = fmaf(al[p + 2], bf2f(src[(long)(p + 2) * E_]), s2);
            s3 = fmaf(al[p + 3], bf2f(src[(long)(p + 3) * E_]), s3);
        }
        long fb_off = (long)b * E_ + e0;
        float g = sigf(fbp[fb_off] + fbp[131072 + fb_off]);
        awe_buf[(long)b * E_ + e0] = f2bf((s0 + s1 + s2 + s3) * g);
    } else {
        if (tid < P_) alphas_out[((long)b * T_ + t) * P_ + tid] = al[tid];
    }
}

// ---------------- gates (awe-only, K-split x2) + light LSTM counter tail ----------------
// grid (64, 2): nblk, kh; wave = quadrant. kh0: awe[0:1024], kh1: awe[1024:2048].
// Last kpart block per nblk reduces gpart + ghp + gemb + biases, applies LSTM.
__global__ void __launch_bounds__(256) k_gates_lstm(
    const u16* __restrict__ awe, const u16* __restrict__ WT_ih,
    const float* __restrict__ ghp, const float* __restrict__ gemb_t,
    const float* __restrict__ b_ih, const float* __restrict__ b_hh,
    float* __restrict__ gpart, int* __restrict__ gcnt,
    float* __restrict__ cbuf, u16* __restrict__ h_new,
    const int* __restrict__ nact, int t)
{
    int Bact = nact[t];
    if (Bact <= 0) return;
    int mmax = (Bact + 15) >> 4;
    int q = threadIdx.x >> 6;
    int lane = threadIdx.x & 63;
    int lr = lane & 15, lk = (lane >> 4) * 8;
    int nblk = blockIdx.x, kh = blockIdx.y;
    int n = nblk * 16 + lr;
    int nc = n < D_ ? n : D_ - 1;
    f32x4 acc[4];
#pragma unroll
    for (int m = 0; m < 4; ++m) acc[m] = (f32x4){0.f, 0.f, 0.f, 0.f};
    // awe rows of W_ih start at 512; kh selects 1024-wide K slice
    const u16* wp = WT_ih + ((long)q * D_ + nc) * XK_ + 512 + kh * 1024;
    const u16* ap = awe + (long)lr * E_ + kh * 1024 + lk;
    for (int k = 0; k < 1024; k += 32) {
        bf16x8 bw = *(const bf16x8*)(wp + k);
#pragma unroll
        for (int m = 0; m < 4; ++m)
            if (m < mmax) {
                bf16x8 aw = *(const bf16x8*)(ap + (long)m * 16 * E_ + k);
                acc[m] = __builtin_amdgcn_mfma_f32_16x16x32_bf16(aw, bw, acc[m], 0, 0, 0);
            }
    }
#pragma unroll
    for (int m = 0; m < 4; ++m) {
        if (m < mmax) {
#pragma unroll
            for (int j = 0; j < 4; ++j) {
                int bb = m * 16 + (lane >> 4) * 4 + j;
                if (bb < Bact)
                    gpart[((long)kh * B_ + bb) * 4096 + q * 1024 + n] = acc[m][j];
            }
        }
    }
    // completion counter: last of the 2 kh blocks for this nblk does the LSTM tail
    __threadfence();
    __syncthreads();
    __shared__ int isLast;
    if (threadIdx.x == 0) isLast = (atomicAdd(&gcnt[nblk], 1) == 1) ? 1 : 0;
    __syncthreads();
    if (!isLast) return;
    __threadfence();   // ensure other block's gpart writes are visible
#pragma unroll
    for (int i = 0; i < 4; ++i) {
        int idx = threadIdx.x + i * 256;     // 1024 (b, col) pairs
        int bb = idx >> 4, col = idx & 15;
        if (bb >= Bact) continue;
        int n2 = nblk * 16 + col;
        if (n2 >= D_) continue;
        const float* gp0 = gpart + (long)bb * 4096 + n2;
        const float* gp1 = gpart + (long)(B_ + bb) * 4096 + n2;
        const float* gh0 = ghp + (long)bb * 4096 + n2;
        const float* gh1 = ghp + (long)(B_ + bb) * 4096 + n2;
        const float* ge  = gemb_t + (long)bb * 4096 + n2;
        float gi = gp0[0]    + gp1[0]    + gh0[0]    + gh1[0]    + ge[0]
                 + b_ih[n2]          + b_hh[n2];
        float gf = gp0[1024] + gp1[1024] + gh0[1024] + gh1[1024] + ge[1024]
                 + b_ih[D_ + n2]     + b_hh[D_ + n2];
        float gg = gp0[2048] + gp1[2048] + gh0[2048] + gh1[2048] + ge[2048]
                 + b_ih[2 * D_ + n2] + b_hh[2 * D_ + n2];
        float go = gp0[3072] + gp1[3072] + gh0[3072] + gh1[3072] + ge[3072]
                 + b_ih[3 * D_ + n2] + b_hh[3 * D_ + n2];
        float c = cbuf[(long)bb * 1024 + n2];
        float cn = sigf(gf) * c + sigf(gi) * tanhf_fast(gg);
        float hn = sigf(go) * tanhf_fast(cn);
        cbuf[(long)bb * 1024 + n2] = cn;
        h_new[(long)bb * 1024 + n2] = f2bf(hn);
    }
    if (threadIdx.x == 0) atomicExch(&gcnt[nblk], 0);   // reset for next step / replay
}

// ---------------- batched FC over all steps: h_all[1..29] @ W_fc -> preds ----------------
// grid (40, 29)
__global__ void __launch_bounds__(256) k_fc_all(
    const u16* __restrict__ h_all, const u16* __restrict__ W,
    const float* __restrict__ bias, float* __restrict__ out_preds,
    const int* __restrict__ nact)
{
    int tslot = blockIdx.y;              // 0..28
    int Bact = nact[tslot];
    if (Bact <= 0) return;
    int mmax = (Bact + 15) >> 4;
    int w = threadIdx.x >> 6, lane = threadIdx.x & 63;
    int lr = lane & 15, lk = (lane >> 4) * 8;
    int n0 = blockIdx.x * 256 + w * 64;
    f32x4 acc[4][4];
#pragma unroll
    for (int i = 0; i < 4; ++i)
#pragma unroll
        for (int j = 0; j < 4; ++j) acc[i][j] = (f32x4){0.f, 0.f, 0.f, 0.f};
    const u16* ap = h_all + ((long)(tslot + 1) * B_ + lr) * 1024 + lk;
    int ncl[4];
#pragma unroll
    for (int nt = 0; nt < 4; ++nt) {
        int n = n0 + nt * 16 + lr;
        ncl[nt] = n < V_ ? n : V_ - 1;
    }
    for (int k = 0; k < 1024; k += 32) {
        bf16x8 af[4], bf[4];
#pragma unroll
        for (int mt = 0; mt < 4; ++mt)
            if (mt < mmax) af[mt] = *(const bf16x8*)(ap + (long)mt * 16 * 1024 + k);
#pragma unroll
        for (int nt = 0; nt < 4; ++nt) bf[nt] = *(const bf16x8*)(W + (long)ncl[nt] * 1024 + lk + k);
#pragma unroll
        for (int mt = 0; mt < 4; ++mt)
            if (mt < mmax)
#pragma unroll
                for (int nt = 0; nt < 4; ++nt)
                    acc[mt][nt] = __builtin_amdgcn_mfma_f32_16x16x32_bf16(af[mt], bf[nt], acc[mt][nt], 0, 0, 0);
    }
#pragma unroll
    for (int nt = 0; nt < 4; ++nt) {
        int n = n0 + nt * 16 + lr;
        if (n >= V_) continue;
        float bv = bias[n];
#pragma unroll
        for (int mt = 0; mt < 4; ++mt) {
            if (mt < mmax) {
#pragma unroll
                for (int j = 0; j < 4; ++j) {
                    int b = mt * 16 + (lane >> 4) * 4 + j;
                    if (b < Bact)
                        out_preds[(long)b * T_ * V_ + (long)tslot * V_ + n] = acc[mt][nt][j] + bv;
                }
            }
        }
    }
}

extern "C" void kernel_launch(void* const* d_in, const int* in_sizes, int n_in,
                              void* d_out, int out_size, void* d_ws, size_t ws_size,
                              hipStream_t stream)
{
    const float* enc    = (const float*)d_in[0];
    const int*   caps   = (const int*)d_in[1];
    const int*   clen   = (const int*)d_in[2];
    const float* arts   = (const float*)d_in[3];
    const float* E_emb  = (const float*)d_in[6];
    const float* W_par  = (const float*)d_in[7];
    const float* b_par  = (const float*)d_in[8];
    const float* W_enc  = (const float*)d_in[9];
    const float* b_enc  = (const float*)d_in[10];
    const float* W_dec  = (const float*)d_in[11];
    const float* b_dec  = (const float*)d_in[12];
    const float* W_full = (const float*)d_in[13];
    const float* b_full = (const float*)d_in[14];
    const float* W_h    = (const float*)d_in[15];
    const float* b_h    = (const float*)d_in[16];
    const float* W_c    = (const float*)d_in[17];
    const float* b_c    = (const float*)d_in[18];
    const float* W_fb   = (const float*)d_in[19];
    const float* b_fb   = (const float*)d_in[20];
    const float* W_ih   = (const float*)d_in[21];
    const float* b_ih   = (const float*)d_in[22];
    const float* W_hh   = (const float*)d_in[23];
    const float* b_hh   = (const float*)d_in[24];
    const float* W_fc   = (const float*)d_in[25];
    const float* b_fc   = (const float*)d_in[26];

    float* out = (float*)d_out;
    float* out_preds  = out;
    float* out_caps   = out + (long)B_ * T_ * V_;
    float* out_dlens  = out_caps + B_ * L_;
    float* out_alphas = out_dlens + B_;
    float* out_sind   = out_alphas + (long)B_ * T_ * P_;

    // workspace layout (float units, 64-aligned)
    float* ws = (float*)d_ws;
    long o = 0;
    auto alloc = [&](long n) { long r = o; o += (n + 63) & ~63L; return r; };
    long o_ints   = alloc(2240);
    long o_decin  = alloc((long)B_ * XK_ / 2);
    long o_hall   = alloc((long)(T_ + 1) * B_ * 1024 / 2);   // bf16 [30][64][1024]
    long o_emball = alloc((long)T_ * B_ * EMB_ / 2);         // bf16 [29][64][512]
    long o_awe    = alloc((long)B_ * E_ / 2);                // bf16 [64][2048]
    long o_c      = alloc((long)B_ * 1024);
    long o_att2p  = alloc((long)2 * B_ * 1024);
    long o_fbp    = alloc((long)2 * B_ * E_);
    long o_ghp    = alloc((long)2 * B_ * 4096);
    long o_gpart  = alloc((long)2 * B_ * 4096);
    long o_gemb   = alloc((long)T_ * B_ * 4096);             // f32 [29][64][4096]
    long o_scores = alloc((long)B_ * P_);
    long o_Abf    = alloc((long)12544 * E_ / 2);
    long o_att1   = alloc((long)12544 * 1024 / 2);
    long o_wtenc  = alloc((long)1024 * 2048 / 2);
    long o_wtdec  = alloc((long)1024 * 1024 / 2);
    long o_wtfb   = alloc((long)2048 * 1024 / 2);
    long o_wtih   = alloc((long)4096 * 2560 / 2);
    long o_wthh   = alloc((long)4096 * 1024 / 2);
    long o_wtfc   = alloc((long)10048 * 1024 / 2);

    int* sort_ind = (int*)(ws + o_ints);
    int* dlens_i  = sort_ind + 64;
    int* nact     = dlens_i + 64;
    int* caps_s   = nact + 32;
    int* gcnt     = caps_s + B_ * L_;
    u16*   dec_in  = (u16*)(ws + o_decin);
    u16*   h_all   = (u16*)(ws + o_hall);
    u16*   emb_all = (u16*)(ws + o_emball);
    u16*   awe_buf = (u16*)(ws + o_awe);
    float* cbuf   = ws + o_c;
    float* att2p  = ws + o_att2p;
    float* fbp    = ws + o_fbp;
    float* ghp    = ws + o_ghp;
    float* gpart  = ws + o_gpart;
    float* gemb_all = ws + o_gemb;
    float* scores = ws + o_scores;
    u16*   A_bf   = (u16*)(ws + o_Abf);
    u16*   att1   = (u16*)(ws + o_att1);
    u16*   WT_enc = (u16*)(ws + o_wtenc);
    u16*   WT_dec = (u16*)(ws + o_wtdec);
    u16*   WT_fb  = (u16*)(ws + o_wtfb);
    u16*   WT_ih  = (u16*)(ws + o_wtih);
    u16*   WT_hh  = (u16*)(ws + o_wthh);
    u16*   WT_fc  = (u16*)(ws + o_wtfc);
    // transient: WT_h / WT_c live in att1's region (overwritten later by k_att1_mfma)
    u16*   WT_h   = att1;
    u16*   WT_c   = att1 + (long)1024 * XK_;

    long n4 = ((long)B_ * T_ * V_ + B_ * L_ + B_ + (long)B_ * T_ * P_ + B_) / 4;
    k_zero<<<dim3((unsigned)((n4 + 255) / 256)), 256, 0, stream>>>((float4*)d_out, n4);
    k_setup<<<1, 64, 0, stream>>>(clen, caps, out_caps, out_dlens, out_sind,
                                  sort_ind, dlens_i, nact, caps_s, gcnt);

    k_encmean<<<dim3(8, 64), 256, 0, stream>>>(enc, sort_ind, dec_in);
    k_ctx<<<dim3(2, 64), 256, 0, stream>>>(arts, W_par, b_par, sort_ind, dec_in);
    k_emb_all<<<dim3(T_, 64), 256, 0, stream>>>(E_emb, caps_s, emb_all);

    dim3 tb(32, 8);
    k_transpose<<<dim3(1024/32, 2560/32), tb, 0, stream>>>(W_h, WT_h, 2548, 1012, 2560, 1024);
    k_transpose<<<dim3(1024/32, 2560/32), tb, 0, stream>>>(W_c, WT_c, 2548, 1012, 2560, 1024);
    // h0 -> h_all slot 0 (bf16, pad-zero cols), c0 -> cbuf (f32)
    k_skinny<0,1,1><<<dim3(16), 256, 0, stream>>>(dec_in, WT_h, XK_, b_h, h_all, 1024L, 0L, D_,
                                                  nact, -1);
    k_skinny<0,0,1><<<dim3(16), 256, 0, stream>>>(dec_in, WT_c, XK_, b_c, cbuf, 1024L, 0L, D_,
                                                  nact, -1);

    k_transpose<<<dim3(1024/32, 2048/32), tb, 0, stream>>>(W_enc, WT_enc, 2048, 1012, 2048, 1024);
    k_transpose<<<dim3(1024/32, 1024/32), tb, 0, stream>>>(W_dec, WT_dec, 1012, 1012, 1024, 1024);
    k_transpose<<<dim3(2048/32, 1024/32), tb, 0, stream>>>(W_fb, WT_fb, 1012, 2048, 1024, 2048);
    k_transpose<<<dim3(4096/32, 2560/32), tb, 0, stream>>>(W_ih, WT_ih, 2560, 4048, 2560, 4096);
    k_transpose<<<dim3(4096/32, 1024/32), tb, 0, stream>>>(W_hh, WT_hh, 1012, 4048, 1024, 4096);
    k_transpose<<<dim3(10048/32, 1024/32), tb, 0, stream>>>(W_fc, WT_fc, 1012, 10000, 1024, 10048);

    k_cvt_enc<<<dim3(2, 12544), 256, 0, stream>>>(enc, sort_ind, A_bf);
    k_att1_mfma<<<dim3(4, 196), 256, 0, stream>>>(A_bf, WT_enc, b_enc, att1);
    k_gemb<<<dim3(16, T_), 256, 0, stream>>>(emb_all, WT_ih, gemb_all);

    for (int t = 0; t < T_; ++t) {
        const u16* h_old = h_all + (long)t * B_ * 1024;
        u16* h_new = h_all + (long)(t + 1) * B_ * 1024;
        const float* gemb_t = gemb_all + (long)t * B_ * 4096;
        k_hg<<<dim3(224), 256, 0, stream>>>(h_old, WT_dec, WT_fb, WT_hh, b_dec, b_fb,
                                            att2p, fbp, ghp, nact, t);
        k_scores<<<dim3(49, 64), 256, 0, stream>>>(att1, att2p, W_full, b_full, scores, nact, t);
        k_awe_x<<<dim3(9, 64), 256, 0, stream>>>(A_bf, scores, fbp, awe_buf,
                                                 out_alphas, nact, t);
        k_gates_lstm<<<dim3(64, 2), 256, 0, stream>>>(awe_buf, WT_ih, ghp, gemb_t,
                                                      b_ih, b_hh, gpart, gcnt, cbuf, h_new,
                                                      nact, t);
    }
    k_fc_all<<<dim3(40, T_), 256, 0, stream>>>(h_all, WT_fc, b_fc, out_preds, nact);
}

// Round 12
// 2842.967 us; speedup vs baseline: 1.0478x; 1.0478x over previous
//
#include <hip/hip_runtime.h>
#include <math.h>

// Problem constants
#define B_   64
#define P_   196      // 14*14 pixels
#define E_   2048
#define L_   30
#define T_   29       // L-1 decode steps
#define V_   10000
#define EMB_ 512
#define AML_ 768
#define ADL_ 500
#define D_   1012     // 512+ADL
#define A_   1012
#define G4_  4048     // 4*D
#define XK_  2560     // EMB+E

typedef unsigned short u16;
typedef __attribute__((ext_vector_type(8))) short bf16x8;
typedef __attribute__((ext_vector_type(4))) float f32x4;

__device__ __forceinline__ float sigf(float x) { return 1.f / (1.f + __expf(-x)); }
__device__ __forceinline__ float tanhf_fast(float x) { return 1.f - 2.f / (__expf(2.f * x) + 1.f); }
__device__ __forceinline__ u16 f2bf(float f) {
    unsigned u = __float_as_uint(f);
    return (u16)((u + 0x7FFFu + ((u >> 16) & 1u)) >> 16);
}
__device__ __forceinline__ float bf2f(u16 v) { return __uint_as_float(((unsigned)v) << 16); }

// ---------------- setup ----------------
__global__ void k_setup(const int* __restrict__ clen, const int* __restrict__ caps,
                        float* __restrict__ out_caps, float* __restrict__ out_dlens,
                        float* __restrict__ out_sind,
                        int* __restrict__ sort_ind, int* __restrict__ dlens_i,
                        int* __restrict__ nact, int* __restrict__ caps_s)
{
    __shared__ int lens[B_];
    int t = threadIdx.x;
    if (t < B_) lens[t] = clen[t];
    __syncthreads();
    if (t < B_) {
        int my = lens[t];
        int rank = 0;
        for (int j = 0; j < B_; ++j) {
            int lj = lens[j];
            if (lj > my || (lj == my && j < t)) rank++;  // stable descending
        }
        sort_ind[rank] = t;
    }
    __syncthreads();
    if (t < B_) {
        int orig = sort_ind[t];
        int dl = lens[orig] - 1;
        dlens_i[t] = dl;
        out_dlens[t] = (float)dl;
        out_sind[t] = (float)orig;
        for (int j = 0; j < L_; ++j) {
            int cv = caps[orig * L_ + j];
            caps_s[t * L_ + j] = cv;
            out_caps[t * L_ + j] = (float)cv;
        }
    }
    __syncthreads();
    if (t < T_) {
        int cnt = 0;
        for (int j = 0; j < B_; ++j) cnt += (dlens_i[j] > t) ? 1 : 0;
        nact[t] = cnt;
    }
}

// ---------------- zero entire output buffer ----------------
__global__ void k_zero(float4* __restrict__ p, long n4)
{
    long i = (long)blockIdx.x * 256 + threadIdx.x;
    if (i < n4) p[i] = make_float4(0.f, 0.f, 0.f, 0.f);
}

// ---------------- gather + fp32->bf16 convert enc rows into sorted order ----------------
__global__ void k_cvt_enc(const float* __restrict__ enc, const int* __restrict__ sort_ind,
                          u16* __restrict__ A_bf)
{
    int row = blockIdx.y;                 // 0..12543  (b*196+p sorted)
    int b = row / 196, p = row - b * 196;
    int e4 = (blockIdx.x * 256 + threadIdx.x) * 4;   // 0..2044
    const float* src = enc + ((long)sort_ind[b] * 196 + p) * E_ + e4;
    float4 v = *(const float4*)src;
    unsigned lo = (unsigned)f2bf(v.x) | ((unsigned)f2bf(v.y) << 16);
    unsigned hi = (unsigned)f2bf(v.z) | ((unsigned)f2bf(v.w) << 16);
    uint2 pk; pk.x = lo; pk.y = hi;
    *(uint2*)(A_bf + (long)row * E_ + e4) = pk;
}

// ---------------- tiled transpose + convert: fp32 [K][N] -> bf16 [Np][Kp] (pads=0) ----
__global__ void k_transpose(const float* __restrict__ src, u16* __restrict__ dst,
                            int K, int N, int Kp, int Np)
{
    __shared__ float tile[32][33];
    int n0 = blockIdx.x * 32, k0 = blockIdx.y * 32;
    int tx = threadIdx.x, ty = threadIdx.y;   // (32,8)
    for (int r = ty; r < 32; r += 8) {
        int k = k0 + r, n = n0 + tx;
        tile[r][tx] = (k < K && n < N) ? src[(long)k * N + n] : 0.f;
    }
    __syncthreads();
    for (int r = ty; r < 32; r += 8) {
        int n = n0 + r, k = k0 + tx;
        if (n < Np && k < Kp) dst[(long)n * Kp + k] = f2bf(tile[tx][r]);
    }
}

// ---------------- enc mean -> dec_in_bf cols [0,2048) ----------------
__global__ void k_encmean(const float* __restrict__ enc, const int* __restrict__ sort_ind,
                          u16* __restrict__ dec_in)
{
    int b = blockIdx.y;
    int e = blockIdx.x * 256 + threadIdx.x;   // < 2048
    int orig = sort_ind[b];
    const float* src = enc + (long)orig * P_ * E_ + e;
    float s = 0.f;
    for (int p = 0; p < P_; ++p) s += src[(long)p * E_];
    dec_in[(long)b * XK_ + e] = f2bf(s * (1.f / 196.f));
}

// ---------------- context -> dec_in_bf cols [2048,2560), pad 0 ----------------
__global__ void k_ctx(const float* __restrict__ arts, const float* __restrict__ W_par,
                      const float* __restrict__ b_par, const int* __restrict__ sort_ind,
                      u16* __restrict__ dec_in)
{
    int b = blockIdx.y;
    int k = blockIdx.x * 256 + threadIdx.x;   // < 512
    if (k >= 512) return;
    float s = 0.f;
    if (k < ADL_) {
        int orig = sort_ind[b];
        const float* ar = arts + (long)orig * AML_;
        s = b_par[k];
        for (int m = 0; m < AML_; ++m) s = fmaf(ar[m], W_par[m * ADL_ + k], s);
    }
    dec_in[(long)b * XK_ + E_ + k] = f2bf(s);
}

// ---------------- emb gather for ALL timesteps (loop-invariant) ----------------
__global__ void k_emb_all(const float* __restrict__ E_emb, const int* __restrict__ caps_s,
                          u16* __restrict__ emb_all)
{
    int t = blockIdx.x;   // 0..28
    int b = blockIdx.y;
    int tok = caps_s[b * L_ + t];
    for (int k = threadIdx.x; k < EMB_; k += 256)
        emb_all[((long)t * B_ + b) * EMB_ + k] = f2bf(E_emb[(long)tok * EMB_ + k]);
}

// ---------------- att1 MFMA with cooperative LDS A-staging + double buffer ----------------
// block = 256 thr, tile M=64 N=256. A-tile [64][32] staged once/block (uint4 = full row).
__global__ void __launch_bounds__(256) k_att1_mfma(
    const u16* __restrict__ A, const u16* __restrict__ W,
    const float* __restrict__ bias, u16* __restrict__ Yb)
{
    __shared__ u16 As[2][64][40];   // 80B row stride: reads & 16B writes bank-even
    int w = threadIdx.x >> 6, lane = threadIdx.x & 63;
    int lr = lane & 15, lk = (lane >> 4) * 8;
    int n0 = blockIdx.x * 256 + w * 64;
    int r0 = blockIdx.y * 64;
    int arow = threadIdx.x >> 2;            // 0..63
    int akseg = (threadIdx.x & 3) * 8;      // 0,8,16,24 (u16 units; 16B each)
    const u16* ag = A + (long)(r0 + arow) * E_ + akseg;

    f32x4 acc[4][4];
#pragma unroll
    for (int i = 0; i < 4; ++i)
#pragma unroll
        for (int j = 0; j < 4; ++j) acc[i][j] = (f32x4){0.f, 0.f, 0.f, 0.f};
    const u16* wp = W + (long)(n0 + lr) * E_ + lk;

    // preload k=0 A-tile (16B per thread -> full 64x32 tile)
    *(uint4*)&As[0][arow][akseg] = *(const uint4*)(ag);
    __syncthreads();

    for (int k = 0; k < E_; k += 32) {
        int buf = (k >> 5) & 1;
        bool more = (k + 32) < E_;
        uint4 pre;
        if (more) pre = *(const uint4*)(ag + k + 32);   // prefetch next A-tile
        bf16x8 bf[4], af[4];
#pragma unroll
        for (int nt = 0; nt < 4; ++nt) bf[nt] = *(const bf16x8*)(wp + (long)nt * 16 * E_ + k);
#pragma unroll
        for (int mt = 0; mt < 4; ++mt) af[mt] = *(const bf16x8*)&As[buf][mt * 16 + lr][lk];
#pragma unroll
        for (int mt = 0; mt < 4; ++mt)
#pragma unroll
            for (int nt = 0; nt < 4; ++nt)
                acc[mt][nt] = __builtin_amdgcn_mfma_f32_16x16x32_bf16(af[mt], bf[nt], acc[mt][nt], 0, 0, 0);
        if (more) *(uint4*)&As[buf ^ 1][arow][akseg] = pre;
        __syncthreads();
    }
#pragma unroll
    for (int mt = 0; mt < 4; ++mt) {
#pragma unroll
        for (int nt = 0; nt < 4; ++nt) {
            int n = n0 + nt * 16 + lr;
            float bv = (n < A_) ? bias[n] : 0.f;
#pragma unroll
            for (int j = 0; j < 4; ++j) {
                int row = r0 + mt * 16 + (lane >> 4) * 4 + j;
                u16 outv = (n < A_) ? f2bf(acc[mt][nt][j] + bv) : (u16)0;
                Yb[(long)row * 1024 + n] = outv;
            }
        }
    }
}

// ---------------- skinny MFMA (h0/c0) ----------------
template <int ACT, int OUT, int PADZ>
__global__ void __launch_bounds__(256) k_skinny(
    const u16* __restrict__ A1, const u16* __restrict__ W1, int K1,
    const float* __restrict__ bias1, void* __restrict__ Yv,
    long ldY, long offY, int Nmax,
    const int* __restrict__ nact, int t)
{
    int Bact = (t >= 0) ? nact[t] : B_;
    if (Bact <= 0) return;
    int mmax = (Bact + 15) >> 4;
    int w = threadIdx.x >> 6, lane = threadIdx.x & 63;
    int lr = lane & 15, lk = (lane >> 4) * 8;
    int n0 = blockIdx.x * 64 + w * 16;
    f32x4 acc[4];
#pragma unroll
    for (int m = 0; m < 4; ++m) acc[m] = (f32x4){0.f, 0.f, 0.f, 0.f};

    int n = n0 + lr;
    int nc = n < Nmax ? n : Nmax - 1;
    const u16* a1p = A1 + (long)lr * K1 + lk;
    const u16* w1p = W1 + (long)nc * K1 + lk;
    for (int k = 0; k < K1; k += 32) {
        bf16x8 bw = *(const bf16x8*)(w1p + k);
#pragma unroll
        for (int m = 0; m < 4; ++m)
            if (m < mmax) {
                bf16x8 aw = *(const bf16x8*)(a1p + (long)m * 16 * K1 + k);
                acc[m] = __builtin_amdgcn_mfma_f32_16x16x32_bf16(aw, bw, acc[m], 0, 0, 0);
            }
    }
    float bv = (n < Nmax) ? bias1[n] : 0.f;
#pragma unroll
    for (int m = 0; m < 4; ++m) {
        if (m < mmax) {
#pragma unroll
            for (int j = 0; j < 4; ++j) {
                int b = m * 16 + (lane >> 4) * 4 + j;
                if (b < Bact) {
                    float v = acc[m][j] + bv;
                    if (ACT == 1) v = sigf(v);
                    if (n < Nmax) {
                        if (OUT == 1) ((u16*)Yv)[(long)b * ldY + offY + n] = f2bf(v);
                        else          ((float*)Yv)[(long)b * ldY + offY + n] = v;
                    } else if (PADZ) {
                        if (OUT == 1) ((u16*)Yv)[(long)b * ldY + offY + n] = 0;
                        else          ((float*)Yv)[(long)b * ldY + offY + n] = 0.f;
                    }
                }
            }
        }
    }
}

// ---------------- batched emb @ W_ih (loop-invariant): gemb_all[t][b][q*1024+n] ----------------
// grid (16, 29)
__global__ void __launch_bounds__(256) k_gemb(
    const u16* __restrict__ emb_all, const u16* __restrict__ WT_ih,
    float* __restrict__ gemb_all)
{
    int t = blockIdx.y;
    int w = threadIdx.x >> 6, lane = threadIdx.x & 63;
    int lr = lane & 15, lk = (lane >> 4) * 8;
    int n0 = blockIdx.x * 256 + w * 64;
    f32x4 acc[4][4];
#pragma unroll
    for (int i = 0; i < 4; ++i)
#pragma unroll
        for (int j = 0; j < 4; ++j) acc[i][j] = (f32x4){0.f, 0.f, 0.f, 0.f};
    const u16* ap = emb_all + ((long)t * B_ + lr) * EMB_ + lk;
    long wrow[4];
#pragma unroll
    for (int nt = 0; nt < 4; ++nt) {
        int j = n0 + nt * 16 + lr;
        int q = j >> 10, d = j & 1023;
        wrow[nt] = (long)q * D_ + (d < D_ ? d : D_ - 1);
    }
    for (int k = 0; k < EMB_; k += 32) {
        bf16x8 af[4], bf[4];
#pragma unroll
        for (int mt = 0; mt < 4; ++mt) af[mt] = *(const bf16x8*)(ap + (long)mt * 16 * EMB_ + k);
#pragma unroll
        for (int nt = 0; nt < 4; ++nt) bf[nt] = *(const bf16x8*)(WT_ih + wrow[nt] * XK_ + lk + k);
#pragma unroll
        for (int mt = 0; mt < 4; ++mt)
#pragma unroll
            for (int nt = 0; nt < 4; ++nt)
                acc[mt][nt] = __builtin_amdgcn_mfma_f32_16x16x32_bf16(af[mt], bf[nt], acc[mt][nt], 0, 0, 0);
    }
#pragma unroll
    for (int nt = 0; nt < 4; ++nt) {
        int j = n0 + nt * 16 + lr;
#pragma unroll
        for (int mt = 0; mt < 4; ++mt) {
#pragma unroll
            for (int jj = 0; jj < 4; ++jj) {
                int b = mt * 16 + (lane >> 4) * 4 + jj;
                gemb_all[((long)t * B_ + b) * 4096 + j] = acc[mt][nt][jj];
            }
        }
    }
}

// ---------------- att2+fb, K-split x2 into partial buffers (round-5 verified) ----------------
__global__ void __launch_bounds__(256) k_att2fb(
    const u16* __restrict__ h_bf, const u16* __restrict__ WT_dec,
    const u16* __restrict__ WT_fb, const float* __restrict__ b_dec,
    const float* __restrict__ b_fb, float* __restrict__ att2p,
    float* __restrict__ fbp, const int* __restrict__ nact, int t)
{
    int Bact = nact[t];
    if (Bact <= 0) return;
    int mmax = (Bact + 15) >> 4;
    int kh = blockIdx.x >= 48;
    int nb = blockIdx.x - (kh ? 48 : 0);
    int isfb = nb >= 16;
    const u16* W = isfb ? WT_fb : WT_dec;
    const float* bias = isfb ? b_fb : b_dec;
    int Nmax = isfb ? E_ : A_;
    int nb2 = isfb ? nb - 16 : nb;
    long ldY = isfb ? (long)E_ : 1024L;
    float* Y = (isfb ? fbp : att2p) + (long)kh * B_ * ldY;

    int w = threadIdx.x >> 6, lane = threadIdx.x & 63;
    int lr = lane & 15, lk = (lane >> 4) * 8;
    int n = nb2 * 64 + w * 16 + lr;
    int nc = n < Nmax ? n : Nmax - 1;
    int k0 = kh * 512;
    f32x4 acc[4];
#pragma unroll
    for (int m = 0; m < 4; ++m) acc[m] = (f32x4){0.f, 0.f, 0.f, 0.f};
    const u16* ap = h_bf + (long)lr * 1024 + k0 + lk;
    const u16* wp = W + (long)nc * 1024 + k0 + lk;
    for (int k = 0; k < 512; k += 32) {
        bf16x8 bw = *(const bf16x8*)(wp + k);
#pragma unroll
        for (int m = 0; m < 4; ++m)
            if (m < mmax) {
                bf16x8 aw = *(const bf16x8*)(ap + (long)m * 16 * 1024 + k);
                acc[m] = __builtin_amdgcn_mfma_f32_16x16x32_bf16(aw, bw, acc[m], 0, 0, 0);
            }
    }
    if (n >= Nmax) return;
    float bv = (kh == 0) ? bias[n] : 0.f;
#pragma unroll
    for (int m = 0; m < 4; ++m) {
        if (m < mmax) {
#pragma unroll
            for (int j = 0; j < 4; ++j) {
                int b = m * 16 + (lane >> 4) * 4 + j;
                if (b < Bact) Y[(long)b * ldY + n] = acc[m][j] + bv;
            }
        }
    }
}

// ---------------- scores: relu(att1_bf + att2p0 + att2p1) @ W_full + b_full ----------------
__global__ void k_scores(const u16* __restrict__ att1, const float* __restrict__ att2p,
                         const float* __restrict__ W_full, const float* __restrict__ b_full,
                         float* __restrict__ scores, const int* __restrict__ nact, int t)
{
    int b = blockIdx.y;
    if (b >= nact[t]) return;
    int wv = threadIdx.x >> 6;
    int lane = threadIdx.x & 63;
    int p = blockIdx.x * 4 + wv;   // 49*4 = 196
    const u16* a1 = att1 + ((long)b * P_ + p) * 1024;
    const float* a20 = att2p + (long)b * 1024;
    const float* a21 = att2p + (long)B_ * 1024 + (long)b * 1024;
    float acc = 0.f;
    for (int j2 = lane; j2 < 506; j2 += 64) {
        unsigned pk = *(const unsigned*)(a1 + 2 * j2);
        float2 p0 = *(const float2*)(a20 + 2 * j2);
        float2 p1 = *(const float2*)(a21 + 2 * j2);
        float2 wv2 = *(const float2*)(W_full + 2 * j2);
        float v0 = bf2f((u16)(pk & 0xFFFF)) + p0.x + p1.x;
        float v1 = bf2f((u16)(pk >> 16)) + p0.y + p1.y;
        v0 = v0 > 0.f ? v0 : 0.f;
        v1 = v1 > 0.f ? v1 : 0.f;
        acc = fmaf(v0, wv2.x, acc);
        acc = fmaf(v1, wv2.y, acc);
    }
    for (int m = 32; m >= 1; m >>= 1) acc += __shfl_xor(acc, m);
    if (lane == 0) scores[b * P_ + p] = acc + b_full[0];
}

// ---------------- awe + local softmax (+alphas) ----------------
// grid (9, 64): blocks 0-7 -> awe_buf cols; block 8 -> alphas_out
__global__ void __launch_bounds__(256) k_awe_x(
    const u16* __restrict__ A_bf, const float* __restrict__ scores,
    const float* __restrict__ fbp, u16* __restrict__ awe_buf,
    float* __restrict__ alphas_out, const int* __restrict__ nact, int t)
{
    int b = blockIdx.y;
    if (b >= nact[t]) return;
    int tid = threadIdx.x;
    int w = tid >> 6, lane = tid & 63;
    __shared__ float al[P_];
    __shared__ float red[4];
    float v = (tid < P_) ? scores[b * P_ + tid] : -1e30f;
    float m = v;
    for (int s = 32; s >= 1; s >>= 1) m = fmaxf(m, __shfl_xor(m, s));
    if (lane == 0) red[w] = m;
    __syncthreads();
    m = fmaxf(fmaxf(red[0], red[1]), fmaxf(red[2], red[3]));
    float e = (tid < P_) ? __expf(v - m) : 0.f;
    float s_ = e;
    for (int s = 32; s >= 1; s >>= 1) s_ += __shfl_xor(s_, s);
    __syncthreads();
    if (lane == 0) red[w] = s_;
    __syncthreads();
    s_ = red[0] + red[1] + red[2] + red[3];
    if (tid < P_) al[tid] = e / s_;
    __syncthreads();

    if (blockIdx.x < 8) {
        int e0 = blockIdx.x * 256 + tid;
        const u16* src = A_bf + (long)b * P_ * E_ + e0;
        float s0 = 0.f, s1 = 0.f, s2 = 0.f, s3 = 0.f;
        for (int p = 0; p < P_; p += 4) {
            s0 = fmaf(al[p],     bf2f(src[(long)p * E_]), s0);
            s1 = fmaf(al[p + 1], bf2f(src[(long)(p + 1) * E_]), s1);
            s2 = fmaf(al[p + 2], bf2f(src[(long)(p + 2) * E_]), s2);
            s3 = fmaf(al[p + 3], bf2f(src[(long)(p + 3) * E_]), s3);
        }
        long fb_off = (long)b * E_ + e0;
        float g = sigf(fbp[fb_off] + fbp[131072 + fb_off]);
        awe_buf[(long)b * E_ + e0] = f2bf((s0 + s1 + s2 + s3) * g);
    } else {
        if (tid < P_) alphas_out[((long)b * T_ + t) * P_ + tid] = al[tid];
    }
}

// ---------------- gates GEMM partials: grid (64, 2), wave = quadrant, K-split across y ----
// kpart0: awe[0:1536] (K=1536); kpart1: awe[1536:2048] (512) + h (1024). emb hoisted (gemb).
__global__ void __launch_bounds__(256) k_gates(
    const u16* __restrict__ awe, const u16* __restrict__ h_old,
    const u16* __restrict__ WT_ih, const u16* __restrict__ WT_hh,
    float* __restrict__ gpart, const int* __restrict__ nact, int t)
{
    int Bact = nact[t];
    if (Bact <= 0) return;
    int mmax = (Bact + 15) >> 4;
    int q = threadIdx.x >> 6;
    int lane = threadIdx.x & 63;
    int lr = lane & 15, lk = (lane >> 4) * 8;
    int kh = blockIdx.y;
    int n = blockIdx.x * 16 + lr;          // 0..1023
    int nc = n < D_ ? n : D_ - 1;
    f32x4 acc[4];
#pragma unroll
    for (int m = 0; m < 4; ++m) acc[m] = (f32x4){0.f, 0.f, 0.f, 0.f};
    const u16* wih = WT_ih + ((long)q * D_ + nc) * XK_;
    const u16* whh = WT_hh + ((long)q * D_ + nc) * 1024;

    if (kh == 0) {
        // awe[0:1536]: W_ih rows 512..2048
        const u16* ap = awe + (long)lr * E_ + lk;
        const u16* w2 = wih + 512;
        for (int k = 0; k < 1536; k += 32) {
            bf16x8 bw = *(const bf16x8*)(w2 + k);
#pragma unroll
            for (int m = 0; m < 4; ++m)
                if (m < mmax) {
                    bf16x8 aw = *(const bf16x8*)(ap + (long)m * 16 * E_ + k);
                    acc[m] = __builtin_amdgcn_mfma_f32_16x16x32_bf16(aw, bw, acc[m], 0, 0, 0);
                }
        }
    } else {
        // awe[1536:2048]: W_ih rows 2048..2560
        const u16* ap2 = awe + (long)lr * E_ + 1536 + lk;
        const u16* w2 = wih + 2048;
        for (int k = 0; k < 512; k += 32) {
            bf16x8 bw = *(const bf16x8*)(w2 + k);
#pragma unroll
            for (int m = 0; m < 4; ++m)
                if (m < mmax) {
                    bf16x8 aw = *(const bf16x8*)(ap2 + (long)m * 16 * E_ + k);
                    acc[m] = __builtin_amdgcn_mfma_f32_16x16x32_bf16(aw, bw, acc[m], 0, 0, 0);
                }
        }
        // h segment: W_hh rows 0..1024
        const u16* ap3 = h_old + (long)lr * 1024 + lk;
        for (int k = 0; k < 1024; k += 32) {
            bf16x8 bw = *(const bf16x8*)(whh + k);
#pragma unroll
            for (int m = 0; m < 4; ++m)
                if (m < mmax) {
                    bf16x8 aw = *(const bf16x8*)(ap3 + (long)m * 16 * 1024 + k);
                    acc[m] = __builtin_amdgcn_mfma_f32_16x16x32_bf16(aw, bw, acc[m], 0, 0, 0);
                }
        }
    }
#pragma unroll
    for (int m = 0; m < 4; ++m) {
        if (m < mmax) {
#pragma unroll
            for (int j = 0; j < 4; ++j) {
                int bb = m * 16 + (lane >> 4) * 4 + j;
                if (bb < Bact)
                    gpart[((long)kh * B_ + bb) * 4096 + q * 1024 + n] = acc[m][j];
            }
        }
    }
}

// ---------------- reduce partials + gemb + LSTM pointwise; h -> h_all slot t+1 ----------------
__global__ void k_lstm_red(const float* __restrict__ gpart, const float* __restrict__ gemb_t,
                           const float* __restrict__ b_ih, const float* __restrict__ b_hh,
                           float* __restrict__ cbuf, u16* __restrict__ h_new,
                           const int* __restrict__ nact, int t)
{
    int b = blockIdx.y;
    if (b >= nact[t]) return;
    int n = blockIdx.x * 256 + threadIdx.x;   // grid.x = 4
    if (n >= D_) return;
    const float* g0 = gpart + (long)b * 4096;
    const float* g1 = gpart + (long)(B_ + b) * 4096;
    const float* ge = gemb_t + (long)b * 4096;
    float gi = g0[n]        + g1[n]        + ge[n]        + b_ih[n]          + b_hh[n];
    float gf = g0[1024 + n] + g1[1024 + n] + ge[1024 + n] + b_ih[D_ + n]     + b_hh[D_ + n];
    float gg = g0[2048 + n] + g1[2048 + n] + ge[2048 + n] + b_ih[2 * D_ + n] + b_hh[2 * D_ + n];
    float go = g0[3072 + n] + g1[3072 + n] + ge[3072 + n] + b_ih[3 * D_ + n] + b_hh[3 * D_ + n];
    float c = cbuf[(long)b * 1024 + n];
    float cn = sigf(gf) * c + sigf(gi) * tanhf_fast(gg);
    float hn = sigf(go) * tanhf_fast(cn);
    cbuf[(long)b * 1024 + n] = cn;
    h_new[(long)b * 1024 + n] = f2bf(hn);
}

// ---------------- batched FC over all steps: h_all[1..29] @ W_fc -> preds ----------------
// grid (40, 29)
__global__ void __launch_bounds__(256) k_fc_all(
    const u16* __restrict__ h_all, const u16* __restrict__ W,
    const float* __restrict__ bias, float* __restrict__ out_preds,
    const int* __restrict__ nact)
{
    int tslot = blockIdx.y;              // 0..28
    int Bact = nact[tslot];
    if (Bact <= 0) return;
    int mmax = (Bact + 15) >> 4;
    int w = threadIdx.x >> 6, lane = threadIdx.x & 63;
    int lr = lane & 15, lk = (lane >> 4) * 8;
    int n0 = blockIdx.x * 256 + w * 64;
    f32x4 acc[4][4];
#pragma unroll
    for (int i = 0; i < 4; ++i)
#pragma unroll
        for (int j = 0; j < 4; ++j) acc[i][j] = (f32x4){0.f, 0.f, 0.f, 0.f};
    const u16* ap = h_all + ((long)(tslot + 1) * B_ + lr) * 1024 + lk;
    int ncl[4];
#pragma unroll
    for (int nt = 0; nt < 4; ++nt) {
        int n = n0 + nt * 16 + lr;
        ncl[nt] = n < V_ ? n : V_ - 1;
    }
    for (int k = 0; k < 1024; k += 32) {
        bf16x8 af[4], bf[4];
#pragma unroll
        for (int mt = 0; mt < 4; ++mt)
            if (mt < mmax) af[mt] = *(const bf16x8*)(ap + (long)mt * 16 * 1024 + k);
#pragma unroll
        for (int nt = 0; nt < 4; ++nt) bf[nt] = *(const bf16x8*)(W + (long)ncl[nt] * 1024 + lk + k);
#pragma unroll
        for (int mt = 0; mt < 4; ++mt)
            if (mt < mmax)
#pragma unroll
                for (int nt = 0; nt < 4; ++nt)
                    acc[mt][nt] = __builtin_amdgcn_mfma_f32_16x16x32_bf16(af[mt], bf[nt], acc[mt][nt], 0, 0, 0);
    }
#pragma unroll
    for (int nt = 0; nt < 4; ++nt) {
        int n = n0 + nt * 16 + lr;
        if (n >= V_) continue;
        float bv = bias[n];
#pragma unroll
        for (int mt = 0; mt < 4; ++mt) {
            if (mt < mmax) {
#pragma unroll
                for (int j = 0; j < 4; ++j) {
                    int b = mt * 16 + (lane >> 4) * 4 + j;
                    if (b < Bact)
                        out_preds[(long)b * T_ * V_ + (long)tslot * V_ + n] = acc[mt][nt][j] + bv;
                }
            }
        }
    }
}

extern "C" void kernel_launch(void* const* d_in, const int* in_sizes, int n_in,
                              void* d_out, int out_size, void* d_ws, size_t ws_size,
                              hipStream_t stream)
{
    const float* enc    = (const float*)d_in[0];
    const int*   caps   = (const int*)d_in[1];
    const int*   clen   = (const int*)d_in[2];
    const float* arts   = (const float*)d_in[3];
    const float* E_emb  = (const float*)d_in[6];
    const float* W_par  = (const float*)d_in[7];
    const float* b_par  = (const float*)d_in[8];
    const float* W_enc  = (const float*)d_in[9];
    const float* b_enc  = (const float*)d_in[10];
    const float* W_dec  = (const float*)d_in[11];
    const float* b_dec  = (const float*)d_in[12];
    const float* W_full = (const float*)d_in[13];
    const float* b_full = (const float*)d_in[14];
    const float* W_h    = (const float*)d_in[15];
    const float* b_h    = (const float*)d_in[16];
    const float* W_c    = (const float*)d_in[17];
    const float* b_c    = (const float*)d_in[18];
    const float* W_fb   = (const float*)d_in[19];
    const float* b_fb   = (const float*)d_in[20];
    const float* W_ih   = (const float*)d_in[21];
    const float* b_ih   = (const float*)d_in[22];
    const float* W_hh   = (const float*)d_in[23];
    const float* b_hh   = (const float*)d_in[24];
    const float* W_fc   = (const float*)d_in[25];
    const float* b_fc   = (const float*)d_in[26];

    float* out = (float*)d_out;
    float* out_preds  = out;
    float* out_caps   = out + (long)B_ * T_ * V_;
    float* out_dlens  = out_caps + B_ * L_;
    float* out_alphas = out_dlens + B_;
    float* out_sind   = out_alphas + (long)B_ * T_ * P_;

    // workspace layout (float units, 64-aligned)
    float* ws = (float*)d_ws;
    long o = 0;
    auto alloc = [&](long n) { long r = o; o += (n + 63) & ~63L; return r; };
    long o_ints   = alloc(2176);
    long o_decin  = alloc((long)B_ * XK_ / 2);
    long o_hall   = alloc((long)(T_ + 1) * B_ * 1024 / 2);   // bf16 [30][64][1024]
    long o_emball = alloc((long)T_ * B_ * EMB_ / 2);         // bf16 [29][64][512]
    long o_awe    = alloc((long)B_ * E_ / 2);                // bf16 [64][2048]
    long o_c      = alloc((long)B_ * 1024);
    long o_att2p  = alloc((long)2 * B_ * 1024);
    long o_fbp    = alloc((long)2 * B_ * E_);
    long o_gpart  = alloc((long)2 * B_ * 4096);
    long o_gemb   = alloc((long)T_ * B_ * 4096);             // f32 [29][64][4096]
    long o_scores = alloc((long)B_ * P_);
    long o_Abf    = alloc((long)12544 * E_ / 2);
    long o_att1   = alloc((long)12544 * 1024 / 2);
    long o_wtenc  = alloc((long)1024 * 2048 / 2);
    long o_wtdec  = alloc((long)1024 * 1024 / 2);
    long o_wtfb   = alloc((long)2048 * 1024 / 2);
    long o_wtih   = alloc((long)4096 * 2560 / 2);
    long o_wthh   = alloc((long)4096 * 1024 / 2);
    long o_wtfc   = alloc((long)10048 * 1024 / 2);

    int* sort_ind = (int*)(ws + o_ints);
    int* dlens_i  = sort_ind + 64;
    int* nact     = dlens_i + 64;
    int* caps_s   = nact + 32;
    u16*   dec_in  = (u16*)(ws + o_decin);
    u16*   h_all   = (u16*)(ws + o_hall);
    u16*   emb_all = (u16*)(ws + o_emball);
    u16*   awe_buf = (u16*)(ws + o_awe);
    float* cbuf   = ws + o_c;
    float* att2p  = ws + o_att2p;
    float* fbp    = ws + o_fbp;
    float* gpart  = ws + o_gpart;
    float* gemb_all = ws + o_gemb;
    float* scores = ws + o_scores;
    u16*   A_bf   = (u16*)(ws + o_Abf);
    u16*   att1   = (u16*)(ws + o_att1);
    u16*   WT_enc = (u16*)(ws + o_wtenc);
    u16*   WT_dec = (u16*)(ws + o_wtdec);
    u16*   WT_fb  = (u16*)(ws + o_wtfb);
    u16*   WT_ih  = (u16*)(ws + o_wtih);
    u16*   WT_hh  = (u16*)(ws + o_wthh);
    u16*   WT_fc  = (u16*)(ws + o_wtfc);
    // transient: WT_h / WT_c live in att1's region (overwritten later by k_att1_mfma)
    u16*   WT_h   = att1;
    u16*   WT_c   = att1 + (long)1024 * XK_;

    long n4 = ((long)B_ * T_ * V_ + B_ * L_ + B_ + (long)B_ * T_ * P_ + B_) / 4;
    k_zero<<<dim3((unsigned)((n4 + 255) / 256)), 256, 0, stream>>>((float4*)d_out, n4);
    k_setup<<<1, 64, 0, stream>>>(clen, caps, out_caps, out_dlens, out_sind,
                                  sort_ind, dlens_i, nact, caps_s);

    k_encmean<<<dim3(8, 64), 256, 0, stream>>>(enc, sort_ind, dec_in);
    k_ctx<<<dim3(2, 64), 256, 0, stream>>>(arts, W_par, b_par, sort_ind, dec_in);
    k_emb_all<<<dim3(T_, 64), 256, 0, stream>>>(E_emb, caps_s, emb_all);

    dim3 tb(32, 8);
    k_transpose<<<dim3(1024/32, 2560/32), tb, 0, stream>>>(W_h, WT_h, 2548, 1012, 2560, 1024);
    k_transpose<<<dim3(1024/32, 2560/32), tb, 0, stream>>>(W_c, WT_c, 2548, 1012, 2560, 1024);
    // h0 -> h_all slot 0 (bf16, pad-zero cols), c0 -> cbuf (f32)
    k_skinny<0,1,1><<<dim3(16), 256, 0, stream>>>(dec_in, WT_h, XK_, b_h, h_all, 1024L, 0L, D_,
                                                  nact, -1);
    k_skinny<0,0,1><<<dim3(16), 256, 0, stream>>>(dec_in, WT_c, XK_, b_c, cbuf, 1024L, 0L, D_,
                                                  nact, -1);

    k_transpose<<<dim3(1024/32, 2048/32), tb, 0, stream>>>(W_enc, WT_enc, 2048, 1012, 2048, 1024);
    k_transpose<<<dim3(1024/32, 1024/32), tb, 0, stream>>>(W_dec, WT_dec, 1012, 1012, 1024, 1024);
    k_transpose<<<dim3(2048/32, 1024/32), tb, 0, stream>>>(W_fb, WT_fb, 1012, 2048, 1024, 2048);
    k_transpose<<<dim3(4096/32, 2560/32), tb, 0, stream>>>(W_ih, WT_ih, 2560, 4048, 2560, 4096);
    k_transpose<<<dim3(4096/32, 1024/32), tb, 0, stream>>>(W_hh, WT_hh, 1012, 4048, 1024, 4096);
    k_transpose<<<dim3(10048/32, 1024/32), tb, 0, stream>>>(W_fc, WT_fc, 1012, 10000, 1024, 10048);

    k_cvt_enc<<<dim3(2, 12544), 256, 0, stream>>>(enc, sort_ind, A_bf);
    k_att1_mfma<<<dim3(4, 196), 256, 0, stream>>>(A_bf, WT_enc, b_enc, att1);
    k_gemb<<<dim3(16, T_), 256, 0, stream>>>(emb_all, WT_ih, gemb_all);

    for (int t = 0; t < T_; ++t) {
        const u16* h_old = h_all + (long)t * B_ * 1024;
        u16* h_new = h_all + (long)(t + 1) * B_ * 1024;
        const float* gemb_t = gemb_all + (long)t * B_ * 4096;
        k_att2fb<<<dim3(96), 256, 0, stream>>>(h_old, WT_dec, WT_fb, b_dec, b_fb,
                                               att2p, fbp, nact, t);
        k_scores<<<dim3(49, 64), 256, 0, stream>>>(att1, att2p, W_full, b_full, scores, nact, t);
        k_awe_x<<<dim3(9, 64), 256, 0, stream>>>(A_bf, scores, fbp, awe_buf,
                                                 out_alphas, nact, t);
        k_gates<<<dim3(64, 2), 256, 0, stream>>>(awe_buf, h_old, WT_ih, WT_hh, gpart, nact, t);
        k_lstm_red<<<dim3(4, 64), 256, 0, stream>>>(gpart, gemb_t, b_ih, b_hh, cbuf, h_new,
                                                    nact, t);
    }
    k_fc_all<<<dim3(40, T_), 256, 0, stream>>>(h_all, WT_fc, b_fc, out_preds, nact);
}